// Round 13
// baseline (77.686 us; speedup 1.0000x reference)
//
#include <hip/hip_runtime.h>

typedef float    f32x4 __attribute__((ext_vector_type(4)));
typedef _Float16 f16x8 __attribute__((ext_vector_type(8)));

constexpr int S_LEN = 2048;
constexpr int DIM   = 64;
constexpr int QBLK  = 128;
constexpr int KBLK  = 64;

// Q pre-scale folds 1/sqrt(D) AND log2(e): softmax runs in exp2 domain.
#define QSCALE 0.1803368801111f
#define THR    11.5f   /* defer-max threshold, log2 units (== 8 nats) */

// R12 per-wave body (verified), now driven by a dynamic work queue:
// grid 768 = 3 blocks/CU resident; 8 per-XCD queues x 128 tiles, popped
// longest-first via atomicAdd. Backfill replaces the static-placement drain
// (R12 measured: 16 waves decaying to 4, time-avg 8.5 = 26% occupancy).
__global__ __launch_bounds__(256, 3)
void fattn(const float* __restrict__ Q, const float* __restrict__ K,
           const float* __restrict__ V, float* __restrict__ Out,
           unsigned* __restrict__ ctrs)
{
    // double-buffered K/V tiles; 32 KiB -> 3 blocks/CU
    __shared__ _Float16 Ks[2][KBLK * DIM];   // [k][d], 128B rows, XOR ((k&7)<<4)
    __shared__ _Float16 Vt[2][DIM * KBLK];   // [d][k-permuted], XOR ((d&7)<<4)
    __shared__ unsigned sTile;

    const int tid  = threadIdx.x;
    const int lane = tid & 63;
    const int wv   = tid >> 6;          // wave 0..3
    const int g    = lane >> 4;
    const int c    = lane & 15;

    // Queue id: blockIdx&7 == XCD under round-robin placement (heuristic for
    // L2 locality only; correctness holds for any placement since each queue
    // is drained exactly once). Queue q owns bh in [q*8, q*8+8).
    const int q8 = blockIdx.x & 7;
    unsigned* ctr = ctrs + q8 * 4;           // 16B-spread counters

    // staging assignments (256 threads, 2 slices each)
    const int krow = tid >> 3;               // 0..31 (+32 for slice 1)
    const int kd0  = (tid & 7) * 8;

    f32x4 kreg[2][2];
    float vreg[2][8];

#define LOAD_KV(KT)                                                            \
    {                                                                          \
        const int ktb_ = (KT) * KBLK;                                          \
        _Pragma("unroll")                                                      \
        for (int sl = 0; sl < 2; ++sl) {                                       \
            const float* kp = Kb + (size_t)(ktb_ + krow + sl * 32) * DIM + kd0;\
            kreg[sl][0] = *(const f32x4*)kp;                                   \
            kreg[sl][1] = *(const f32x4*)(kp + 4);                             \
            const float* vp = Vb + (size_t)(ktb_ + sl * 32 + wv * 4) * DIM + lane; \
            _Pragma("unroll")                                                  \
            for (int mi = 0; mi < 8; ++mi)                                     \
                vreg[sl][mi] = vp[(size_t)((mi >> 2) * 16 + (mi & 3)) * DIM];  \
        }                                                                      \
    }

#define WRITE_KV(B)                                                            \
    {                                                                          \
        _Pragma("unroll")                                                      \
        for (int sl = 0; sl < 2; ++sl) {                                       \
            const int row = krow + sl * 32;                                    \
            f16x8 kb;                                                          \
            _Pragma("unroll")                                                  \
            for (int i = 0; i < 4; ++i) {                                      \
                kb[i]     = (_Float16)kreg[sl][0][i];                          \
                kb[i + 4] = (_Float16)kreg[sl][1][i];                          \
            }                                                                  \
            *(f16x8*)((char*)Ks[B] + row * 128 + ((kd0 * 2) ^ ((row & 7) << 4))) = kb; \
            f16x8 vb;                                                          \
            _Pragma("unroll")                                                  \
            for (int mi = 0; mi < 8; ++mi) vb[mi] = (_Float16)vreg[sl][mi];    \
            const int oct = wv + sl * 4;                                       \
            *(f16x8*)((char*)Vt[B] + lane * 128 + ((oct * 16) ^ ((lane & 7) << 4))) = vb; \
        }                                                                      \
    }

    #pragma unroll 1
    for (;;) {
        // ---- pop next tile (longest-first: ti>>3 = 0 -> qt 15) ----
        if (tid == 0) sTile = atomicAdd(ctr, 1u);
        __syncthreads();
        const unsigned ti = sTile;
        if (ti >= 128u) break;
        const int bh = q8 * 8 + (int)(ti & 7u);
        const int qt = 15 - (int)(ti >> 3);
        const int qbase = qt * QBLK;
        const int qw    = qbase + wv * 32;       // this wave's 32 q-rows
        const int nkt   = 2 * qt + 2;
        const size_t base = (size_t)bh * (S_LEN * DIM);
        const float* Kb = K + base;
        const float* Vb = V + base;

        // ---- Q fragments (pre-scaled) ----
        f16x8 qf[2][2];                          // [dc][qh]
        #pragma unroll
        for (int qh = 0; qh < 2; ++qh) {
            const float* qp = Q + base + (size_t)(qw + qh * 16 + c) * DIM + g * 8;
            #pragma unroll
            for (int dc = 0; dc < 2; ++dc) {
                const f32x4 f0 = *(const f32x4*)(qp + dc * 32);
                const f32x4 f1 = *(const f32x4*)(qp + dc * 32 + 4);
                f16x8 q;
                #pragma unroll
                for (int i = 0; i < 4; ++i) {
                    q[i]     = (_Float16)(f0[i] * QSCALE);
                    q[i + 4] = (_Float16)(f1[i] * QSCALE);
                }
                qf[dc][qh] = q;
            }
        }

        f32x4 o[4][2];                           // [dt][qh]
        #pragma unroll
        for (int dt = 0; dt < 4; ++dt)
            #pragma unroll
            for (int qh = 0; qh < 2; ++qh) o[dt][qh] = (f32x4){0.f, 0.f, 0.f, 0.f};
        float m[2] = {-INFINITY, -INFINITY};
        float l[2] = {0.f, 0.f};

        // ---- pipeline prologue ----
        LOAD_KV(0)
        WRITE_KV(0)
        LOAD_KV(1)                  // nkt >= 2 always
        __syncthreads();            // buf0 ready

        #pragma unroll 1
        for (int kt = 0; kt < nkt; ++kt) {
            const int cur = kt & 1;
            const int ktb = kt * KBLK;
            if (kt + 1 < nkt) WRITE_KV(cur ^ 1)  // regs hold tile kt+1
            if (kt + 2 < nkt) LOAD_KV(kt + 2)

            if (ktb <= qw + 31) {
                // ---- S^T = K Q^T: lane holds P[k=ktb+ct*16+g*4+r][q=qw+qh*16+c] ----
                f32x4 s[4][2];
                __builtin_amdgcn_s_setprio(1);
                #pragma unroll
                for (int ct = 0; ct < 4; ++ct) {
                    const int r = ct * 16 + c;
                    const char* kp = (const char*)Ks[cur] + r * 128;
                    const f16x8 kf0 = *(const f16x8*)(kp + ((g * 16)      ^ ((r & 7) << 4)));
                    const f16x8 kf1 = *(const f16x8*)(kp + ((64 + g * 16) ^ ((r & 7) << 4)));
                    #pragma unroll
                    for (int qh = 0; qh < 2; ++qh) {
                        f32x4 acc = (f32x4){0.f, 0.f, 0.f, 0.f};
                        acc = __builtin_amdgcn_mfma_f32_16x16x32_f16(kf0, qf[0][qh], acc, 0, 0, 0);
                        acc = __builtin_amdgcn_mfma_f32_16x16x32_f16(kf1, qf[1][qh], acc, 0, 0, 0);
                        s[ct][qh] = acc;
                    }
                }
                __builtin_amdgcn_s_setprio(0);

                // ---- causal mask (diagonal-touching tiles only) ----
                if (ktb + KBLK - 1 > qw) {
                    #pragma unroll
                    for (int ct = 0; ct < 4; ++ct)
                        #pragma unroll
                        for (int qh = 0; qh < 2; ++qh)
                            #pragma unroll
                            for (int r = 0; r < 4; ++r)
                                if (ktb + ct * 16 + g * 4 + r > qw + qh * 16 + c)
                                    s[ct][qh][r] = -INFINITY;
                }

                // ---- online softmax in exp2 domain (per-lane state) ----
                float rm[2];
                #pragma unroll
                for (int qh = 0; qh < 2; ++qh) {
                    float v = s[0][qh][0];
                    #pragma unroll
                    for (int ct = 0; ct < 4; ++ct)
                        #pragma unroll
                        for (int r = 0; r < 4; ++r) v = fmaxf(v, s[ct][qh][r]);
                    v = fmaxf(v, __shfl_xor(v, 16));
                    v = fmaxf(v, __shfl_xor(v, 32));
                    rm[qh] = v;
                }
                const float need = fmaxf(rm[0] - m[0], rm[1] - m[1]);
                if (!__all(need <= THR)) {       // defer-max (T13)
                    #pragma unroll
                    for (int qh = 0; qh < 2; ++qh) {
                        const float mn = fmaxf(m[qh], rm[qh]);
                        const float sc = __builtin_amdgcn_exp2f(m[qh] - mn);
                        m[qh] = mn;
                        l[qh] *= sc;
                        #pragma unroll
                        for (int dt = 0; dt < 4; ++dt)
                            #pragma unroll
                            for (int r = 0; r < 4; ++r) o[dt][qh][r] *= sc;
                    }
                }
                float rs[2] = {0.f, 0.f};
                #pragma unroll
                for (int ct = 0; ct < 4; ++ct)
                    #pragma unroll
                    for (int qh = 0; qh < 2; ++qh)
                        #pragma unroll
                        for (int r = 0; r < 4; ++r) {
                            const float pv = __builtin_amdgcn_exp2f(s[ct][qh][r] - m[qh]);
                            s[ct][qh][r] = pv;
                            rs[qh] += pv;
                        }
                #pragma unroll
                for (int qh = 0; qh < 2; ++qh) {
                    float v = rs[qh];
                    v += __shfl_xor(v, 16);
                    v += __shfl_xor(v, 32);
                    l[qh] += v;
                }

                // ---- P -> f16 B-fragments, fully in-lane (k-permuted Vt matches) ----
                f16x8 pa[2][2];                  // [qh][kc]
                #pragma unroll
                for (int qh = 0; qh < 2; ++qh)
                    #pragma unroll
                    for (int kc = 0; kc < 2; ++kc) {
                        f16x8 pk;
                        #pragma unroll
                        for (int r = 0; r < 4; ++r) {
                            pk[r]     = (_Float16)s[2 * kc][qh][r];
                            pk[r + 4] = (_Float16)s[2 * kc + 1][qh][r];
                        }
                        pa[qh][kc] = pk;
                    }

                // ---- O^T += V^T P^T ----
                __builtin_amdgcn_s_setprio(1);
                #pragma unroll
                for (int dt = 0; dt < 4; ++dt) {
                    const int dd = dt * 16 + c;
                    const char* vp = (const char*)Vt[cur] + dd * 128;
                    #pragma unroll
                    for (int kc = 0; kc < 2; ++kc) {
                        const f16x8 vf = *(const f16x8*)(vp +
                            ((kc * 64 + g * 16) ^ ((dd & 7) << 4)));
                        #pragma unroll
                        for (int qh = 0; qh < 2; ++qh)
                            o[dt][qh] = __builtin_amdgcn_mfma_f32_16x16x32_f16(
                                vf, pa[qh][kc], o[dt][qh], 0, 0, 0);
                    }
                }
                __builtin_amdgcn_s_setprio(0);
            }
            __syncthreads();
        }

        // ---- epilogue: lane holds O^T[d=dt*16+g*4+r][q=qw+qh*16+c] ----
        #pragma unroll
        for (int qh = 0; qh < 2; ++qh) {
            const float invl = 1.f / l[qh];
            const size_t qoff = base + (size_t)(qw + qh * 16 + c) * DIM;
            #pragma unroll
            for (int dt = 0; dt < 4; ++dt) {
                f32x4 ov;
                #pragma unroll
                for (int r = 0; r < 4; ++r) ov[r] = o[dt][qh][r] * invl;
                *(f32x4*)(Out + qoff + dt * 16 + g * 4) = ov;
            }
        }
    }
#undef LOAD_KV
#undef WRITE_KV
}

extern "C" void kernel_launch(void* const* d_in, const int* in_sizes, int n_in,
                              void* d_out, int out_size, void* d_ws, size_t ws_size,
                              hipStream_t stream)
{
    const float* Q = (const float*)d_in[0];
    const float* K = (const float*)d_in[1];
    const float* V = (const float*)d_in[2];
    float* Out = (float*)d_out;
    // mask (d_in[3]) is the fixed causal mask -> hardcoded in-kernel
    // 8 queue counters, 16B-spread, zeroed every launch (deterministic).
    hipMemsetAsync(d_ws, 0, 128, stream);
    fattn<<<dim3(768), 256, 0, stream>>>(Q, K, V, Out, (unsigned*)d_ws);
}

// Round 15
// 77.558 us; speedup vs baseline: 1.0017x; 1.0017x over previous
//
#include <hip/hip_runtime.h>

typedef float    f32x4 __attribute__((ext_vector_type(4)));
typedef _Float16 f16x8 __attribute__((ext_vector_type(8)));
typedef __fp16   h16x2 __attribute__((ext_vector_type(2)));   // cvt_pkrtz native type

constexpr int S_LEN = 2048;
constexpr int DIM   = 64;
constexpr int QBLK  = 128;
constexpr int KBLK  = 64;

// Q pre-scale folds 1/sqrt(D) AND log2(e): softmax runs in exp2 domain.
#define QSCALE 0.1803368801111f
#define THR    11.5f   /* defer-max threshold, log2 units (== 8 nats) */

// pack 8 f32 -> f16x8 via v_cvt_pkrtz (1 VALU per 2 elements, RTZ <=1ulp)
static __device__ __forceinline__ f16x8 pack8(f32x4 a, f32x4 b) {
    union { h16x2 h[4]; f16x8 v; } u;
    u.h[0] = __builtin_amdgcn_cvt_pkrtz(a[0], a[1]);
    u.h[1] = __builtin_amdgcn_cvt_pkrtz(a[2], a[3]);
    u.h[2] = __builtin_amdgcn_cvt_pkrtz(b[0], b[1]);
    u.h[3] = __builtin_amdgcn_cvt_pkrtz(b[2], b[3]);
    return u.v;
}
static __device__ __forceinline__ f16x8 pack8f(const float* v) {
    union { h16x2 h[4]; f16x8 v8; } u;
    u.h[0] = __builtin_amdgcn_cvt_pkrtz(v[0], v[1]);
    u.h[1] = __builtin_amdgcn_cvt_pkrtz(v[2], v[3]);
    u.h[2] = __builtin_amdgcn_cvt_pkrtz(v[4], v[5]);
    u.h[3] = __builtin_amdgcn_cvt_pkrtz(v[6], v[7]);
    return u.v8;
}

// R12 verified body. New: (1) LDS padded to 53248 B -> 3 blocks/CU resident,
// grid 1024 > 768 slots -> HW dispatcher backfills (heavy-first => short
// tiles form the tail); (2) QK^T reads precede staging writes (kills LDS
// may-alias ordering on the critical path), staging hides under softmax;
// (3) cvt_pkrtz packing halves conversion VALU. (256,1): no VGPR cap.
__global__ __launch_bounds__(256, 1)
void fattn(const float* __restrict__ Q, const float* __restrict__ K,
           const float* __restrict__ V, float* __restrict__ Out)
{
    __shared__ _Float16 Ks[2][KBLK * DIM];   // [k][d], 128B rows, XOR ((k&7)<<4)
    __shared__ _Float16 Vt[2][DIM * KBLK];   // [d][k-permuted], XOR ((d&7)<<4)
    __shared__ unsigned ldspad[5120];        // +20 KB -> 53248 B total: 3 blocks/CU

    const int tid  = threadIdx.x;
    const int lane = tid & 63;
    const int wv   = tid >> 6;          // wave 0..3
    const int g    = lane >> 4;
    const int c    = lane & 15;

    // keep the pad allocated (volatile read, value swallowed by empty asm)
    unsigned pd = ((volatile unsigned*)ldspad)[0];
    asm volatile("" :: "v"(pd));

    // 1024 blocks round-robin XCDs (id&7). XCD x owns bh in [x*8, x*8+8).
    // Heavy q-tiles dispatch first; backfilled tail = 2..8-iter tiles.
    const int id    = blockIdx.x;
    const int local = id >> 3;                   // 0..127 within XCD
    const int bh    = (id & 7) * 8 + (local & 7);
    const int qt    = 15 - (local >> 3);         // 15,...,0 (heavy first)
    const int qbase = qt * QBLK;
    const int qw    = qbase + wv * 32;           // this wave's 32 q-rows
    const int nkt   = 2 * qt + 2;
    const size_t base = (size_t)bh * (S_LEN * DIM);

    // ---- Q fragments (pre-scaled) ----
    f16x8 qf[2][2];                              // [dc][qh]
    #pragma unroll
    for (int qh = 0; qh < 2; ++qh) {
        const float* qp = Q + base + (size_t)(qw + qh * 16 + c) * DIM + g * 8;
        #pragma unroll
        for (int dc = 0; dc < 2; ++dc) {
            const f32x4 f0 = *(const f32x4*)(qp + dc * 32);
            const f32x4 f1 = *(const f32x4*)(qp + dc * 32 + 4);
            qf[dc][qh] = pack8(f0 * QSCALE, f1 * QSCALE);
        }
    }

    // staging assignments (256 threads, 2 slices each)
    const int krow = tid >> 3;                   // 0..31 (+32 for slice 1)
    const int kd0  = (tid & 7) * 8;
    const float* Kb = K + base;
    const float* Vb = V + base;

    f32x4 kreg[2][2];
    float vreg[2][8];

#define LOAD_KV(KT)                                                            \
    {                                                                          \
        const int ktb_ = (KT) * KBLK;                                          \
        _Pragma("unroll")                                                      \
        for (int sl = 0; sl < 2; ++sl) {                                       \
            const float* kp = Kb + (size_t)(ktb_ + krow + sl * 32) * DIM + kd0;\
            kreg[sl][0] = *(const f32x4*)kp;                                   \
            kreg[sl][1] = *(const f32x4*)(kp + 4);                             \
            const float* vp = Vb + (size_t)(ktb_ + sl * 32 + wv * 4) * DIM + lane; \
            _Pragma("unroll")                                                  \
            for (int mi = 0; mi < 8; ++mi)                                     \
                vreg[sl][mi] = vp[(size_t)((mi >> 2) * 16 + (mi & 3)) * DIM];  \
        }                                                                      \
    }

#define WRITE_KV(B)                                                            \
    {                                                                          \
        _Pragma("unroll")                                                      \
        for (int sl = 0; sl < 2; ++sl) {                                       \
            const int row = krow + sl * 32;                                    \
            const f16x8 kb = pack8(kreg[sl][0], kreg[sl][1]);                  \
            *(f16x8*)((char*)Ks[B] + row * 128 + ((kd0 * 2) ^ ((row & 7) << 4))) = kb; \
            const f16x8 vb = pack8f(vreg[sl]);                                 \
            const int oct = wv + sl * 4;                                       \
            *(f16x8*)((char*)Vt[B] + lane * 128 + ((oct * 16) ^ ((lane & 7) << 4))) = vb; \
        }                                                                      \
    }

    f32x4 o[4][2];                               // [dt][qh]
    #pragma unroll
    for (int dt = 0; dt < 4; ++dt)
        #pragma unroll
        for (int qh = 0; qh < 2; ++qh) o[dt][qh] = (f32x4){0.f, 0.f, 0.f, 0.f};
    float m[2] = {-INFINITY, -INFINITY};
    float l[2] = {0.f, 0.f};

    // ---- pipeline prologue ----
    LOAD_KV(0)
    WRITE_KV(0)
    LOAD_KV(1)                      // nkt >= 2 always
    __syncthreads();                // buf0 ready

    for (int kt = 0; kt < nkt; ++kt) {
        const int cur = kt & 1;
        const int ktb = kt * KBLK;
        const bool active = (ktb <= qw + 31);

        f32x4 s[4][2];
        if (active) {
            // ---- S^T = K Q^T (reads of buf cur BEFORE any staging writes) ----
            __builtin_amdgcn_s_setprio(1);
            #pragma unroll
            for (int ct = 0; ct < 4; ++ct) {
                const int r = ct * 16 + c;
                const char* kp = (const char*)Ks[cur] + r * 128;
                const f16x8 kf0 = *(const f16x8*)(kp + ((g * 16)      ^ ((r & 7) << 4)));
                const f16x8 kf1 = *(const f16x8*)(kp + ((64 + g * 16) ^ ((r & 7) << 4)));
                #pragma unroll
                for (int qh = 0; qh < 2; ++qh) {
                    f32x4 acc = (f32x4){0.f, 0.f, 0.f, 0.f};
                    acc = __builtin_amdgcn_mfma_f32_16x16x32_f16(kf0, qf[0][qh], acc, 0, 0, 0);
                    acc = __builtin_amdgcn_mfma_f32_16x16x32_f16(kf1, qf[1][qh], acc, 0, 0, 0);
                    s[ct][qh] = acc;
                }
            }
            __builtin_amdgcn_s_setprio(0);

            // ---- causal mask (diagonal-touching tiles only) ----
            if (ktb + KBLK - 1 > qw) {
                #pragma unroll
                for (int ct = 0; ct < 4; ++ct)
                    #pragma unroll
                    for (int qh = 0; qh < 2; ++qh)
                        #pragma unroll
                        for (int r = 0; r < 4; ++r)
                            if (ktb + ct * 16 + g * 4 + r > qw + qh * 16 + c)
                                s[ct][qh][r] = -INFINITY;
            }
        }

        // ---- staging (writes buf cur^1; hidden under softmax below) ----
        if (kt + 1 < nkt) WRITE_KV(cur ^ 1)      // regs hold tile kt+1
        if (kt + 2 < nkt) LOAD_KV(kt + 2)

        if (active) {
            // ---- online softmax in exp2 domain (per-lane state) ----
            float rm[2];
            #pragma unroll
            for (int qh = 0; qh < 2; ++qh) {
                float v = s[0][qh][0];
                #pragma unroll
                for (int ct = 0; ct < 4; ++ct)
                    #pragma unroll
                    for (int r = 0; r < 4; ++r) v = fmaxf(v, s[ct][qh][r]);
                v = fmaxf(v, __shfl_xor(v, 16));
                v = fmaxf(v, __shfl_xor(v, 32));
                rm[qh] = v;
            }
            const float need = fmaxf(rm[0] - m[0], rm[1] - m[1]);
            if (!__all(need <= THR)) {           // defer-max (T13)
                #pragma unroll
                for (int qh = 0; qh < 2; ++qh) {
                    const float mn = fmaxf(m[qh], rm[qh]);
                    const float sc = __builtin_amdgcn_exp2f(m[qh] - mn);
                    m[qh] = mn;
                    l[qh] *= sc;
                    #pragma unroll
                    for (int dt = 0; dt < 4; ++dt)
                        #pragma unroll
                        for (int r = 0; r < 4; ++r) o[dt][qh][r] *= sc;
                }
            }
            float rs[2] = {0.f, 0.f};
            #pragma unroll
            for (int ct = 0; ct < 4; ++ct)
                #pragma unroll
                for (int qh = 0; qh < 2; ++qh)
                    #pragma unroll
                    for (int r = 0; r < 4; ++r) {
                        const float pv = __builtin_amdgcn_exp2f(s[ct][qh][r] - m[qh]);
                        s[ct][qh][r] = pv;
                        rs[qh] += pv;
                    }
            #pragma unroll
            for (int qh = 0; qh < 2; ++qh) {
                float v = rs[qh];
                v += __shfl_xor(v, 16);
                v += __shfl_xor(v, 32);
                l[qh] += v;
            }

            // ---- P -> f16 B-fragments, fully in-lane (k-permuted Vt matches) ----
            f16x8 pa[2][2];                      // [qh][kc]
            #pragma unroll
            for (int qh = 0; qh < 2; ++qh)
                #pragma unroll
                for (int kc = 0; kc < 2; ++kc)
                    pa[qh][kc] = pack8(s[2 * kc][qh], s[2 * kc + 1][qh]);

            // ---- O^T += V^T P^T ----
            __builtin_amdgcn_s_setprio(1);
            #pragma unroll
            for (int dt = 0; dt < 4; ++dt) {
                const int dd = dt * 16 + c;
                const char* vp = (const char*)Vt[cur] + dd * 128;
                #pragma unroll
                for (int kc = 0; kc < 2; ++kc) {
                    const f16x8 vf = *(const f16x8*)(vp +
                        ((kc * 64 + g * 16) ^ ((dd & 7) << 4)));
                    #pragma unroll
                    for (int qh = 0; qh < 2; ++qh)
                        o[dt][qh] = __builtin_amdgcn_mfma_f32_16x16x32_f16(
                            vf, pa[qh][kc], o[dt][qh], 0, 0, 0);
                }
            }
            __builtin_amdgcn_s_setprio(0);
        }
        __syncthreads();
    }

    // ---- epilogue: lane holds O^T[d=dt*16+g*4+r][q=qw+qh*16+c] ----
    #pragma unroll
    for (int qh = 0; qh < 2; ++qh) {
        const float invl = 1.f / l[qh];
        const size_t qoff = base + (size_t)(qw + qh * 16 + c) * DIM;
        #pragma unroll
        for (int dt = 0; dt < 4; ++dt) {
            f32x4 ov;
            #pragma unroll
            for (int r = 0; r < 4; ++r) ov[r] = o[dt][qh][r] * invl;
            *(f32x4*)(Out + qoff + dt * 16 + g * 4) = ov;
        }
    }
#undef LOAD_KV
#undef WRITE_KV
}

extern "C" void kernel_launch(void* const* d_in, const int* in_sizes, int n_in,
                              void* d_out, int out_size, void* d_ws, size_t ws_size,
                              hipStream_t stream)
{
    const float* Q = (const float*)d_in[0];
    const float* K = (const float*)d_in[1];
    const float* V = (const float*)d_in[2];
    float* Out = (float*)d_out;
    // mask (d_in[3]) is the fixed causal mask -> hardcoded in-kernel
    fattn<<<dim3(1024), 256, 0, stream>>>(Q, K, V, Out);
}